// Round 8
// baseline (397.500 us; speedup 1.0000x reference)
//
#include <hip/hip_runtime.h>
#include <hip/hip_bf16.h>

#define N_ 4
#define T_ 4096
#define D_ 512
#define H_ 8
#define DH_ 64
#define NH_ 4
#define NB_ 64
#define CS_ 256
#define L_ 16384

typedef unsigned short u16;
typedef unsigned int u32;
typedef __attribute__((ext_vector_type(8))) short short8;
typedef __attribute__((ext_vector_type(8))) _Float16 half8;
typedef __attribute__((ext_vector_type(4))) float f32x4;
typedef __attribute__((ext_vector_type(2))) float f32x2;

__device__ __forceinline__ u16 f2bf(float x){
    union { float f; u32 u; } c; c.f = x;
    u32 u = c.u;
    u32 r = (u + 0x7FFFu + ((u >> 16) & 1u)) >> 16;
    return (u16)r;
}
__device__ __forceinline__ float bf2f(u16 b){
    union { u32 u; float f; } c; c.u = ((u32)b) << 16;
    return c.f;
}
__device__ __forceinline__ u16 f2h(float x){
    _Float16 h = (_Float16)x;
    u16 r; __builtin_memcpy(&r, &h, 2); return r;
}

// packed fp32 FMA: acc.{lo,hi} += a_scalar * b.{lo,hi}
// NOTE (r4 data): half-rate on gfx950 (4 cyc) — win vs scalar is issue-slot
// economy only. k_q FMA-pipe floor ~55us.
#define PK_LO(acc, a, b) \
    asm("v_pk_fma_f32 %0, %1, %2, %0 op_sel:[0,0,0] op_sel_hi:[0,1,1]" \
        : "+v"(acc) : "v"(a), "v"(b))
#define PK_HI(acc, a, b) \
    asm("v_pk_fma_f32 %0, %1, %2, %0 op_sel:[1,0,0] op_sel_hi:[1,1,1]" \
        : "+v"(acc) : "v"(a), "v"(b))

// sVt bank-spread swizzle (r2: fixed 16-way conflict in k_attn V staging)
#define VSWZ(d) ((((d) >> 3) ^ ((d) & 7)))

// ---------------------------------------------------------------------------
// K0b: transpose Wv -> wvt [512 n][512 k] f16
// ---------------------------------------------------------------------------
__global__ __launch_bounds__(256) void k_decWv(const float* __restrict__ Wv,
        u16* __restrict__ wvt){
    __shared__ float tile[32][33];
    const int tid = threadIdx.x;
    const int kt = blockIdx.x * 32, nt = blockIdx.y * 32;
    const int tx = tid & 31, ty = tid >> 5;
    #pragma unroll
    for (int i = 0; i < 4; ++i)
        tile[ty + i * 8][tx] = Wv[(size_t)(kt + ty + i * 8) * 512 + nt + tx];
    __syncthreads();
    #pragma unroll
    for (int i = 0; i < 4; ++i){
        int n = ty + i * 8;
        wvt[(size_t)(nt + n) * 512 + kt + tx] = f2h(tile[tx][n]);
    }
}

// ---------------------------------------------------------------------------
// K1 (ROLE-SPLIT): grid 1024 blocks; role 0 = Q GEMM (fp32 VALU), role 1 =
//   V GEMM (f16 MFMA, x->f16 folded into staging). m114 pipe-heterogeneous
//   co-residency; r7-verified neutral-to-positive, fewer dispatches.
// ---------------------------------------------------------------------------
__global__ __launch_bounds__(512, 4) void k_qv(const float* __restrict__ x,
        const float* __restrict__ Wq, const float* __restrict__ bq,
        const u16* __restrict__ wvt, const float* __restrict__ bv,
        float* __restrict__ Q, u16* __restrict__ Qbf, float* __restrict__ qinv,
        u16* __restrict__ Vbf){
    __shared__ __align__(16) char uLDS[33792];

    const int bid = blockIdx.x;
    const int role = (bid >> 8) & 1;
    const int id = ((bid >> 9) << 8) | (bid & 255);   // [0,512) per role
    const int mb = (id & 127) * 128;
    const int nbi = id >> 7;
    const int nb = nbi * 128;
    const int tid = threadIdx.x;

    if (role == 0){
        // ================= Q = x@W_Q + b_Q (fp32, exact-class) ===========
        typedef float (*pan_t)[16][132];
        pan_t sA = (pan_t)uLDS;                       // sA[p][k][m]
        pan_t sB = (pan_t)(uLDS + 16896);             // sB[p][k][n]
        const int tx = tid & 31, ty = tid >> 5;
        f32x2 acc2[8][2];
        #pragma unroll
        for (int i = 0; i < 8; ++i){
            acc2[i][0] = (f32x2){0.f, 0.f};
            acc2[i][1] = (f32x2){0.f, 0.f};
        }
        const int mA = tid >> 2, kA = (tid & 3) * 4;
        const int kB = tid >> 5, cB = (tid & 31) * 4;
        const float* xp = &x[(size_t)(mb + mA) * 512 + kA];
        const float* wp = &Wq[(size_t)kB * 512 + nb + cB];
        float4 pa = *(const float4*)xp;
        float4 pb = *(const float4*)wp;

        for (int k0 = 0; k0 < 512; k0 += 16){
            const int p = (k0 >> 4) & 1;
            sA[p][kA + 0][mA] = pa.x; sA[p][kA + 1][mA] = pa.y;
            sA[p][kA + 2][mA] = pa.z; sA[p][kA + 3][mA] = pa.w;
            *(float4*)&sB[p][kB][cB] = pb;
            __syncthreads();
            if (k0 < 496){
                pa = *(const float4*)(xp + k0 + 16);
                pb = *(const float4*)(wp + (size_t)(k0 + 16) * 512);
            }
            #pragma unroll
            for (int kk = 0; kk < 16; ++kk){
                float4 va0 = *(const float4*)&sA[p][kk][ty * 8];
                float4 va1 = *(const float4*)&sA[p][kk][ty * 8 + 4];
                float4 vb  = *(const float4*)&sB[p][kk][tx * 4];
                f32x2 a2[4], b2[2];
                a2[0] = (f32x2){va0.x, va0.y}; a2[1] = (f32x2){va0.z, va0.w};
                a2[2] = (f32x2){va1.x, va1.y}; a2[3] = (f32x2){va1.z, va1.w};
                b2[0] = (f32x2){vb.x, vb.y};   b2[1] = (f32x2){vb.z, vb.w};
                #pragma unroll
                for (int i = 0; i < 8; ++i){
                    if (i & 1){
                        PK_HI(acc2[i][0], a2[i >> 1], b2[0]);
                        PK_HI(acc2[i][1], a2[i >> 1], b2[1]);
                    } else {
                        PK_LO(acc2[i][0], a2[i >> 1], b2[0]);
                        PK_LO(acc2[i][1], a2[i >> 1], b2[1]);
                    }
                }
            }
            // no trailing barrier: next iteration writes the other buffer
        }

        float4 vbq = *(const float4*)&bq[nb + tx * 4];
        const int h = nbi * 2 + (tx >> 4);
        const int d0 = (tx & 15) * 4;
        #pragma unroll
        for (int i = 0; i < 8; ++i){
            float o0 = acc2[i][0].x + vbq.x;
            float o1 = acc2[i][0].y + vbq.y;
            float o2 = acc2[i][1].x + vbq.z;
            float o3 = acc2[i][1].y + vbq.w;
            int m = mb + ty * 8 + i;
            int n = m >> 12, t = m & (T_ - 1);
            float4 q4; q4.x = o0; q4.y = o1; q4.z = o2; q4.w = o3;
            *(float4*)&Q[(size_t)m * 512 + nb + tx * 4] = q4;
            float ss = o0 * o0 + o1 * o1 + o2 * o2 + o3 * o3;
            #pragma unroll
            for (int s = 8; s >= 1; s >>= 1) ss += __shfl_xor(ss, s, 64);
            size_t rowb = (size_t)(h * N_ + n) * T_ + t;
            if ((tx & 15) == 0) qinv[rowb] = 1.f / (sqrtf(ss) + 1e-6f);
            ushort4 qb4;
            qb4.x = f2bf(o0); qb4.y = f2bf(o1); qb4.z = f2bf(o2); qb4.w = f2bf(o3);
            *(ushort4*)&Qbf[rowb * 64 + d0] = qb4;
        }
    } else {
        // ================= V = x@W_V + b_V (f16 MFMA) ====================
        if (tid >= 256) return;        // exited waves don't hold s_barrier
        u16* sA = (u16*)uLDS;                         // [128*40]
        u16* sB = (u16*)(uLDS + 10240);               // [128*40]
        const int w = tid >> 6, lane = tid & 63;
        const int quad = lane >> 4, cc = lane & 15;
        const int wm = (w & 1) * 64, wn = (w >> 1) * 64;
        f32x4 acc[4][4];
        #pragma unroll
        for (int i = 0; i < 4; ++i)
            #pragma unroll
            for (int j = 0; j < 4; ++j) acc[i][j] = (f32x4){0.f, 0.f, 0.f, 0.f};

        for (int k0 = 0; k0 < 512; k0 += 32){
            #pragma unroll
            for (int i = 0; i < 2; ++i){
                int idx = i * 256 + tid;               // 0..511
                int m = idx >> 2, ks = idx & 3;
                const float* xs = &x[(size_t)(mb + m) * 512 + k0 + ks * 8];
                float4 f0 = *(const float4*)xs;
                float4 f1 = *(const float4*)(xs + 4);
                short8 s;                               // == k_decXf's f2h
                s[0] = (short)f2h(f0.x); s[1] = (short)f2h(f0.y);
                s[2] = (short)f2h(f0.z); s[3] = (short)f2h(f0.w);
                s[4] = (short)f2h(f1.x); s[5] = (short)f2h(f1.y);
                s[6] = (short)f2h(f1.z); s[7] = (short)f2h(f1.w);
                *(short8*)&sA[m * 40 + ks * 8] = s;
                *(short8*)&sB[m * 40 + ks * 8] =
                    *(const short8*)&wvt[(size_t)(nb + m) * 512 + k0 + ks * 8];
            }
            __syncthreads();
            half8 a[4], b[4];
            #pragma unroll
            for (int i = 0; i < 4; ++i){
                a[i] = *(const half8*)&sA[(wm + i * 16 + cc) * 40 + quad * 8];
                b[i] = *(const half8*)&sB[(wn + i * 16 + cc) * 40 + quad * 8];
            }
            #pragma unroll
            for (int i = 0; i < 4; ++i)
                #pragma unroll
                for (int j = 0; j < 4; ++j)
                    acc[i][j] = __builtin_amdgcn_mfma_f32_16x16x32_f16(a[i], b[j], acc[i][j], 0, 0, 0);
            __syncthreads();
        }
        #pragma unroll
        for (int i = 0; i < 4; ++i)
            #pragma unroll
            for (int j = 0; j < 4; ++j){
                int c = nb + wn + j * 16 + cc;
                int hh = c >> 6, d = c & 63;
                float bi = bv[c];
                #pragma unroll
                for (int r = 0; r < 4; ++r){
                    int m = mb + wm + i * 16 + quad * 4 + r;
                    int n = m >> 12, t = m & (T_ - 1);
                    Vbf[((size_t)(hh * N_ + n) * T_ + t) * 64 + d] = f2bf(acc[i][j][r] + bi);
                }
            }
    }
}

// ---------------------------------------------------------------------------
// K2: rotations + argmax -> buckets[h][n][j*T + t]  (fp32, exact tie rules)
//     r8: 64-t tile (Rs staging amortized 2x); LDS 48KB -> 3 blocks/CU.
// ---------------------------------------------------------------------------
__global__ __launch_bounds__(256) void k_rot(const float* __restrict__ Q,
        const float* __restrict__ rot, int* __restrict__ buckets){
    const int tb = blockIdx.x * 64;
    const int n = blockIdx.y, h = blockIdx.z;
    const int hn = h * N_ + n;
    __shared__ float Rs[64 * 128];    // [f][i][jj]: f*128 + i*4 + jj
    __shared__ float Qs[64][64];
    const int tid = threadIdx.x;
    const float* rh = rot + (size_t)h * (64 * 128);   // [f][jj][i] contiguous
    for (int idx = tid; idx < 8192; idx += 256){
        int f = idx >> 7, rem = idx & 127, jj = rem >> 5, i2 = rem & 31;
        Rs[f * 128 + i2 * 4 + jj] = rh[idx];
    }
    for (int i = tid; i < 4096; i += 256){
        int t = i >> 6, f = i & 63;
        Qs[t][f] = Q[(size_t)(n * T_ + tb + t) * 512 + h * 64 + f];
    }
    __syncthreads();
    const int tx = tid & 31, tg = tid >> 5;   // tg: 8 groups of 4 t's
    for (int half = 0; half < 2; ++half){
        f32x2 r2[4][2];                        // [tt][jj-pair]
        #pragma unroll
        for (int tt = 0; tt < 4; ++tt){
            r2[tt][0] = (f32x2){0.f, 0.f};
            r2[tt][1] = (f32x2){0.f, 0.f};
        }
        for (int f = 0; f < 64; f += 2){
            f32x2 qf[4];
            #pragma unroll
            for (int tt = 0; tt < 4; ++tt)
                qf[tt] = *(const f32x2*)&Qs[half * 32 + tg * 4 + tt][f];
            float4 rv0 = *(const float4*)&Rs[f * 128 + tx * 4];
            float4 rv1 = *(const float4*)&Rs[(f + 1) * 128 + tx * 4];
            f32x2 b0[2], b1[2];
            b0[0] = (f32x2){rv0.x, rv0.y}; b0[1] = (f32x2){rv0.z, rv0.w};
            b1[0] = (f32x2){rv1.x, rv1.y}; b1[1] = (f32x2){rv1.z, rv1.w};
            #pragma unroll
            for (int tt = 0; tt < 4; ++tt){
                PK_LO(r2[tt][0], qf[tt], b0[0]);   // f   contribution
                PK_LO(r2[tt][1], qf[tt], b0[1]);
                PK_HI(r2[tt][0], qf[tt], b1[0]);   // f+1 contribution
                PK_HI(r2[tt][1], qf[tt], b1[1]);
            }
        }
        #pragma unroll
        for (int tt = 0; tt < 4; ++tt){
            #pragma unroll
            for (int jj = 0; jj < 4; ++jj){
                float rval = (jj < 2) ? r2[tt][0][jj] : r2[tt][1][jj - 2];
                // argmax over concat(r, -r); first-occurrence tie-break
                float bv = rval; int bi = tx;
                float nv = -bv;
                if (nv > bv){ bv = nv; bi = 32 + tx; }
                #pragma unroll
                for (int m = 16; m >= 1; m >>= 1){
                    float ov = __shfl_xor(bv, m, 32);
                    int   oi = __shfl_xor(bi, m, 32);
                    if (ov > bv || (ov == bv && oi < bi)){ bv = ov; bi = oi; }
                }
                if (tx == 0){
                    int t = tb + half * 32 + tg * 4 + tt;
                    buckets[(size_t)hn * L_ + jj * T_ + t] = bi + jj * 64;
                }
            }
        }
    }
}

// ---------------------------------------------------------------------------
// K3a: per-(hn,tile) 256-bin histogram. tile = 256 consecutive items.
// ---------------------------------------------------------------------------
__global__ __launch_bounds__(256) void k_hist(const int* __restrict__ buckets,
        int* __restrict__ hist){
    const int tile = blockIdx.x, hn = blockIdx.y;
    const int tid = threadIdx.x;
    __shared__ int h[256];
    h[tid] = 0;
    __syncthreads();
    int b = buckets[(size_t)hn * L_ + tile * 256 + tid];
    atomicAdd(&h[b], 1);
    __syncthreads();
    hist[((size_t)hn * 64 + tile) * 256 + tid] = h[tid];
}

// ---------------------------------------------------------------------------
// K3b: per-hn: in-place exclusive prefix of hist over tiles (per bucket),
//      then block scan of bucket totals -> bucketStart[hn][256]
// ---------------------------------------------------------------------------
__global__ __launch_bounds__(256) void k_scan(int* __restrict__ hist,
        int* __restrict__ bucketStart){
    const int hn = blockIdx.x;
    const int b = threadIdx.x;
    int* hh = hist + (size_t)hn * 64 * 256;
    int run = 0;
    for (int tl = 0; tl < 64; ++tl){
        int v = hh[tl * 256 + b];
        hh[tl * 256 + b] = run;      // exclusive within-bucket tile prefix
        run += v;
    }
    __shared__ int s[256];
    s[b] = run;
    __syncthreads();
    for (int off = 1; off < 256; off <<= 1){
        int add = (b >= off) ? s[b - off] : 0;
        __syncthreads();
        s[b] += add;
        __syncthreads();
    }
    bucketStart[hn * 256 + b] = s[b] - run;   // exclusive bucket start
}

// ---------------------------------------------------------------------------
// K3c: stable scatter: sticker[pos] = item index
// ---------------------------------------------------------------------------
__global__ __launch_bounds__(256) void k_scatter(const int* __restrict__ buckets,
        const int* __restrict__ offs, const int* __restrict__ bucketStart,
        int* __restrict__ sticker){
    const int tile = blockIdx.x, hn = blockIdx.y;
    const int tid = threadIdx.x;
    __shared__ int sb[256];
    const int i = tile * 256 + tid;
    const int b = buckets[(size_t)hn * L_ + i];
    sb[tid] = b;
    __syncthreads();
    int rank = 0;
    #pragma unroll 8
    for (int j = 0; j < 256; ++j){
        int v = sb[j];                         // broadcast read
        rank += (j < tid && v == b) ? 1 : 0;
    }
    int pos = bucketStart[hn * 256 + b]
            + offs[((size_t)hn * 64 + tile) * 256 + b]
            + rank;
    sticker[(size_t)hn * L_ + pos] = i;
}

// ---------------------------------------------------------------------------
// K4: chunked attention via MFMA. block = (chunk, n, h). 64 q x 128 k, DH=64
//     sP aliases sQ; o_hash layout [hn][t][jj][d] (r8, for k_comb bursts);
//     s_setprio around MFMA clusters (T5).
// ---------------------------------------------------------------------------
__global__ __launch_bounds__(256) void k_attn(const u16* __restrict__ Qbf,
        const u16* __restrict__ Vbf, const float* __restrict__ qinv,
        const int* __restrict__ buckets, const int* __restrict__ sticker,
        u16* __restrict__ o_hash, float* __restrict__ logit_hash){
    const int blk_c = blockIdx.x, n = blockIdx.y, h = blockIdx.z;
    const int hn = h * N_ + n;
    const int tid = threadIdx.x;
    const int w = tid >> 6, lane = tid & 63;
    const int quad = lane >> 4, cc = lane & 15;

    __shared__ __align__(16) u16 sQP[128 * 64];
    __shared__ __align__(16) u16 sVt[64 * 128];   // row = d, col = key row (V^T)
    __shared__ int s_idx[128], s_buck[128], s_t[128];
    __shared__ float s_inv[128];
    __shared__ float s_lse[64];
    u16* const sQ = sQP;
    u16* const sP = sQP;

    if (tid < 128){
        int cprev = (blk_c + CS_ - 1) & (CS_ - 1);
        int pos = (tid < 64) ? blk_c * 64 + tid : cprev * 64 + (tid - 64);
        int idx = sticker[(size_t)hn * L_ + pos];
        s_idx[tid] = idx;
        s_buck[tid] = buckets[(size_t)hn * L_ + idx];
        int t = idx & (T_ - 1);
        s_t[tid] = t;
        s_inv[tid] = qinv[(size_t)hn * T_ + t] * 0.125f;   // exact pow2 fold
    }
    __syncthreads();

    // ---- stage Q rows (b128) and V transposed (scalar b16) ----
    const int r0 = tid >> 3, l8 = tid & 7;
    #pragma unroll
    for (int it = 0; it < 4; ++it){
        int r = it * 32 + r0;
        size_t gb = ((size_t)hn * T_ + s_t[r]) * 64 + l8 * 8;
        short8 qv = *(const short8*)&Qbf[gb];
        *(short8*)&sQ[r * 64 + ((l8 ^ (r & 7)) * 8)] = qv;
        short8 vv = *(const short8*)&Vbf[gb];
        #pragma unroll
        for (int i = 0; i < 8; ++i){
            int d = l8 * 8 + i;
            sVt[d * 128 + (((r >> 3) ^ VSWZ(d)) * 8) + (r & 7)] = (u16)vv[i];
        }
    }
    __syncthreads();

    // ---- QK^T: wave w -> q-tile w; 2 k-chunks x 8 k-tiles ----
    f32x4 dacc[8];
    #pragma unroll
    for (int j = 0; j < 8; ++j) dacc[j] = (f32x4){0.f, 0.f, 0.f, 0.f};
    const int qrow = w * 16 + cc;
    __builtin_amdgcn_s_setprio(1);
    #pragma unroll
    for (int kc = 0; kc < 2; ++kc){
        short8 afrag = *(const short8*)&sQ[qrow * 64 + (((kc * 4 + quad) ^ (cc & 7)) * 8)];
        #pragma unroll
        for (int kt = 0; kt < 8; ++kt){
            int krow = kt * 16 + cc;
            short8 bfrag = *(const short8*)&sQ[krow * 64 + (((kc * 4 + quad) ^ (cc & 7)) * 8)];
            dacc[kt] = __builtin_amdgcn_mfma_f32_16x16x32_bf16(afrag, bfrag, dacc[kt], 0, 0, 0);
        }
    }
    __builtin_amdgcn_s_setprio(0);

    // ---- scale + masks + row softmax (rows: q = w*16 + quad*4 + reg) ----
    int bq[4], tq[4];
    #pragma unroll
    for (int r = 0; r < 4; ++r){
        int q = w * 16 + quad * 4 + r;
        bq[r] = s_buck[q]; tq[r] = s_t[q];
    }
    float mrow[4] = {-1e30f, -1e30f, -1e30f, -1e30f};
    #pragma unroll
    for (int kt = 0; kt < 8; ++kt){
        int kk = kt * 16 + cc;
        float inv = s_inv[kk];
        int bk = s_buck[kk], tk = s_t[kk];
        #pragma unroll
        for (int r = 0; r < 4; ++r){
            float d = dacc[kt][r] * inv;
            if (bk != bq[r]) d = -1e9f;
            if (tk == tq[r]) d = -1e-5f;
            dacc[kt][r] = d;
            mrow[r] = fmaxf(mrow[r], d);
        }
    }
    #pragma unroll
    for (int r = 0; r < 4; ++r)
        #pragma unroll
        for (int m = 8; m >= 1; m >>= 1)
            mrow[r] = fmaxf(mrow[r], __shfl_xor(mrow[r], m, 64));
    // exp once: keep p = exp(d - m) in dacc, sum it
    float srow[4] = {0.f, 0.f, 0.f, 0.f};
    #pragma unroll
    for (int kt = 0; kt < 8; ++kt)
        #pragma unroll
        for (int r = 0; r < 4; ++r){
            float e = __expf(dacc[kt][r] - mrow[r]);
            dacc[kt][r] = e;
            srow[r] += e;
        }
    #pragma unroll
    for (int r = 0; r < 4; ++r)
        #pragma unroll
        for (int m = 8; m >= 1; m >>= 1)
            srow[r] += __shfl_xor(srow[r], m, 64);
    float lse[4], pscale[4];
    #pragma unroll
    for (int r = 0; r < 4; ++r){
        lse[r] = mrow[r] + __logf(srow[r]);
        pscale[r] = 1.f / srow[r];
    }
    if (cc == 0){
        #pragma unroll
        for (int r = 0; r < 4; ++r) s_lse[w * 16 + quad * 4 + r] = lse[r];
    }

    // all waves' QK^T reads of sQ must complete before sP overwrites it;
    // barrier placed after softmax so that VALU overlaps slower waves' MFMA.
    __syncthreads();

    // ---- probs -> sP (C-layout scatter into swizzled A-layout tile) ----
    #pragma unroll
    for (int kt = 0; kt < 8; ++kt){
        int kk = kt * 16 + cc;
        #pragma unroll
        for (int r = 0; r < 4; ++r){
            int q = w * 16 + quad * 4 + r;
            sP[q * 128 + (((kk >> 3) ^ (q & 15)) * 8) + (kk & 7)] =
                f2bf(dacc[kt][r] * pscale[r]);
        }
    }
    __syncthreads();

    // ---- PV: wave w -> q-tile w; 4 k-chunks x 4 n-tiles ----
    f32x4 oacc[4];
    #pragma unroll
    for (int j = 0; j < 4; ++j) oacc[j] = (f32x4){0.f, 0.f, 0.f, 0.f};
    __builtin_amdgcn_s_setprio(1);
    #pragma unroll
    for (int kc = 0; kc < 4; ++kc){
        short8 afrag = *(const short8*)&sP[qrow * 128 + (((kc * 4 + quad) ^ cc) * 8)];
        #pragma unroll
        for (int nt = 0; nt < 4; ++nt){
            int d = nt * 16 + cc;
            short8 bfrag = *(const short8*)&sVt[d * 128 + (((kc * 4 + quad) ^ VSWZ(d)) * 8)];
            oacc[nt] = __builtin_amdgcn_mfma_f32_16x16x32_bf16(afrag, bfrag, oacc[nt], 0, 0, 0);
        }
    }
    __builtin_amdgcn_s_setprio(0);

    // ---- epilogue: scatter o (bf16) and logits; layout [hn][t][jj][d] ----
    #pragma unroll
    for (int r = 0; r < 4; ++r){
        int q = w * 16 + quad * 4 + r;
        int si = s_idx[q];
        int jj = si >> 12; int t = si & (T_ - 1);
        size_t base = (((size_t)hn * T_ + t) * NH_ + jj) * 64;
        #pragma unroll
        for (int nt = 0; nt < 4; ++nt)
            o_hash[base + nt * 16 + cc] = f2bf(oacc[nt][r]);
    }
    if (tid < 64){
        int si = s_idx[tid]; int jj = si >> 12; int t = si & (T_ - 1);
        logit_hash[((size_t)hn * T_ + t) * NH_ + jj] = s_lse[tid];
    }
}

// ---------------------------------------------------------------------------
// K5: combine over NH hash rounds per head + fused LayerNorm.
//     r8: 4 tokens/block, one wave per token, no LDS, no barriers.
//     Per-head hash-softmax via intra-quad shfl (lanes h*4+j hold pw[h][j]);
//     LN via full-wave shfl reduce. o_hash layout [hn][t][jj][d] gives each
//     head one 512B contiguous read burst.
// ---------------------------------------------------------------------------
__global__ __launch_bounds__(256) void k_comb(const u16* __restrict__ o_hash,
        const float* __restrict__ logit_hash, const float* __restrict__ gamma,
        const float* __restrict__ beta, float* __restrict__ out){
    const int n = blockIdx.y;
    const int tid = threadIdx.x;
    const int w = tid >> 6, lane = tid & 63;
    const int t = blockIdx.x * 4 + w;

    // lanes 0..31: pw for (h = lane>>2, j = lane&3)
    float pwv = 0.f;
    if (lane < 32){
        int h = lane >> 2, j = lane & 3;
        pwv = logit_hash[((size_t)(h * N_ + n) * T_ + t) * NH_ + j];
    }
    // per-head lse within each quad of lanes
    float m = fmaxf(pwv, __shfl_xor(pwv, 1, 64));
    m = fmaxf(m, __shfl_xor(m, 2, 64));
    float e = __expf(pwv - m);
    float l = e + __shfl_xor(e, 1, 64);
    l += __shfl_xor(l, 2, 64);
    float wgt = __expf(pwv - (m + __logf(l)));   // lane h*4+j: weight[h][j]

    // combine: lane owns channel (h, d=lane) for h = 0..7
    float acc[8];
    #pragma unroll
    for (int h = 0; h < 8; ++h){
        size_t base = ((size_t)(h * N_ + n) * T_ + t) * (NH_ * 64);
        float a = 0.f;
        #pragma unroll
        for (int j = 0; j < 4; ++j){
            float wj = __shfl(wgt, h * 4 + j, 64);
            a += wj * bf2f(o_hash[base + j * 64 + lane]);
        }
        acc[h] = a;
    }
    // LayerNorm over 512 channels: per-lane 8, then wave reduce
    float s1 = 0.f, s2 = 0.f;
    #pragma unroll
    for (int h = 0; h < 8; ++h){ s1 += acc[h]; s2 += acc[h] * acc[h]; }
    #pragma unroll
    for (int ms = 32; ms >= 1; ms >>= 1){
        s1 += __shfl_xor(s1, ms, 64);
        s2 += __shfl_xor(s2, ms, 64);
    }
    float mu = s1 / 512.f;
    float var = s2 / 512.f - mu * mu;
    float rs = 1.f / sqrtf(var + 1e-3f);
    #pragma unroll
    for (int h = 0; h < 8; ++h){
        int c = h * 64 + lane;
        out[((size_t)(n * T_ + t)) * 512 + c] =
            gamma[c] * (acc[h] - mu) * rs + beta[c];
    }
}

// ---------------------------------------------------------------------------
extern "C" void kernel_launch(void* const* d_in, const int* in_sizes, int n_in,
                              void* d_out, int out_size, void* d_ws, size_t ws_size,
                              hipStream_t stream){
    const float* x     = (const float*)d_in[0];
    const float* Wq    = (const float*)d_in[1];
    const float* bq    = (const float*)d_in[2];
    const float* Wv    = (const float*)d_in[3];
    const float* bv    = (const float*)d_in[4];
    const float* gamma = (const float*)d_in[5];
    const float* beta  = (const float*)d_in[6];
    const float* rot   = (const float*)d_in[7];
    char* ws = (char*)d_ws;
    // workspace layout. Time-disjoint overlap: Q fp32 [0,33.5MB) dead after
    // k_rot; o_hash [0,67.1MB) written only by k_attn (later in stream).
    float* Q        = (float*)(ws + 0);               // 33,554,432 B (k_qv..k_rot)
    u16*   o_hash   = (u16*)  (ws + 0);               // 67,108,864 B (k_attn..k_comb)
    u16*   Qbf      = (u16*)  (ws + 67108864);        // 16,777,216 B
    u16*   Vbf      = (u16*)  (ws + 83886080);        // 16,777,216 B
    float* qinv     = (float*)(ws + 100663296);       //    524,288 B
    int*   buckets  = (int*)  (ws + 101187584);       //  2,097,152 B
    int*   sticker  = (int*)  (ws + 103284736);       //  2,097,152 B
    float* logit    = (float*)(ws + 105381888);       //  2,097,152 B
    int*   hist     = (int*)  (ws + 107479040);       //  2,097,152 B
    int*   bstart   = (int*)  (ws + 109576192);       //     32,768 B
    u16*   wvt      = (u16*)  (ws + 109608960);       //    524,288 B

    hipLaunchKernelGGL(k_decWv,   dim3(16, 16),     dim3(256), 0, stream,
                       Wv, wvt);
    hipLaunchKernelGGL(k_qv,      dim3(1024),       dim3(512), 0, stream,
                       x, Wq, bq, wvt, bv, Q, Qbf, qinv, Vbf);
    hipLaunchKernelGGL(k_rot,     dim3(64, 4, 8),   dim3(256), 0, stream,
                       Q, rot, buckets);
    hipLaunchKernelGGL(k_hist,    dim3(64, 32),     dim3(256), 0, stream,
                       buckets, hist);
    hipLaunchKernelGGL(k_scan,    dim3(32),         dim3(256), 0, stream,
                       hist, bstart);
    hipLaunchKernelGGL(k_scatter, dim3(64, 32),     dim3(256), 0, stream,
                       buckets, hist, bstart, sticker);
    hipLaunchKernelGGL(k_attn,    dim3(256, 4, 8),  dim3(256), 0, stream,
                       Qbf, Vbf, qinv, buckets, sticker, o_hash, logit);
    hipLaunchKernelGGL(k_comb,    dim3(1024, 4),    dim3(256), 0, stream,
                       o_hash, logit, gamma, beta, (float*)d_out);
}

// Round 10
// 370.933 us; speedup vs baseline: 1.0716x; 1.0716x over previous
//
#include <hip/hip_runtime.h>
#include <hip/hip_bf16.h>

#define N_ 4
#define T_ 4096
#define D_ 512
#define H_ 8
#define DH_ 64
#define NH_ 4
#define NB_ 64
#define CS_ 256
#define L_ 16384

typedef unsigned short u16;
typedef unsigned int u32;
typedef __attribute__((ext_vector_type(8))) short short8;
typedef __attribute__((ext_vector_type(8))) _Float16 half8;
typedef __attribute__((ext_vector_type(4))) float f32x4;
typedef __attribute__((ext_vector_type(2))) float f32x2;

__device__ __forceinline__ u16 f2bf(float x){
    union { float f; u32 u; } c; c.f = x;
    u32 u = c.u;
    u32 r = (u + 0x7FFFu + ((u >> 16) & 1u)) >> 16;
    return (u16)r;
}
__device__ __forceinline__ float bf2f(u16 b){
    union { u32 u; float f; } c; c.u = ((u32)b) << 16;
    return c.f;
}
__device__ __forceinline__ u16 f2h(float x){
    _Float16 h = (_Float16)x;
    u16 r; __builtin_memcpy(&r, &h, 2); return r;
}

// packed fp32 FMA: acc.{lo,hi} += a_scalar * b.{lo,hi}
// NOTE (r4 data): half-rate on gfx950 (4 cyc) — win vs scalar is issue-slot
// economy only. k_q FMA-pipe floor ~55us.
#define PK_LO(acc, a, b) \
    asm("v_pk_fma_f32 %0, %1, %2, %0 op_sel:[0,0,0] op_sel_hi:[0,1,1]" \
        : "+v"(acc) : "v"(a), "v"(b))
#define PK_HI(acc, a, b) \
    asm("v_pk_fma_f32 %0, %1, %2, %0 op_sel:[1,0,0] op_sel_hi:[1,1,1]" \
        : "+v"(acc) : "v"(a), "v"(b))

// sVt bank-spread swizzle (r2: fixed 16-way conflict in k_attn V staging)
#define VSWZ(d) ((((d) >> 3) ^ ((d) & 7)))

// ---------------------------------------------------------------------------
// K0b: transpose Wv -> wvt [512 n][512 k] f16
// ---------------------------------------------------------------------------
__global__ __launch_bounds__(256) void k_decWv(const float* __restrict__ Wv,
        u16* __restrict__ wvt){
    __shared__ float tile[32][33];
    const int tid = threadIdx.x;
    const int kt = blockIdx.x * 32, nt = blockIdx.y * 32;
    const int tx = tid & 31, ty = tid >> 5;
    #pragma unroll
    for (int i = 0; i < 4; ++i)
        tile[ty + i * 8][tx] = Wv[(size_t)(kt + ty + i * 8) * 512 + nt + tx];
    __syncthreads();
    #pragma unroll
    for (int i = 0; i < 4; ++i){
        int n = ty + i * 8;
        wvt[(size_t)(nt + n) * 512 + kt + tx] = f2h(tile[tx][n]);
    }
}

// ---------------------------------------------------------------------------
// K1 (ROLE-SPLIT): grid 1024 blocks; role 0 = Q GEMM (fp32 VALU), role 1 =
//   V GEMM (f16 MFMA, x->f16 folded into staging). m114 pipe-heterogeneous
//   co-residency. r9: Q-role kk loop software-pipelined — read kk+1's three
//   float4 LDS operands into rotation regs BEFORE the 32-FMA block, so the
//   ~120cyc LDS latency hides under the 128cyc FMA block (was: VALUBusy 60%,
//   VGPR 36 — compiler under-pipelined). Accumulation order unchanged ->
//   Q bit-identical. (r9 bench was an infra failure; resubmitted verbatim.)
// ---------------------------------------------------------------------------
__global__ __launch_bounds__(512, 4) void k_qv(const float* __restrict__ x,
        const float* __restrict__ Wq, const float* __restrict__ bq,
        const u16* __restrict__ wvt, const float* __restrict__ bv,
        float* __restrict__ Q, u16* __restrict__ Qbf, float* __restrict__ qinv,
        u16* __restrict__ Vbf){
    __shared__ __align__(16) char uLDS[33792];

    const int bid = blockIdx.x;
    const int role = (bid >> 8) & 1;
    const int id = ((bid >> 9) << 8) | (bid & 255);   // [0,512) per role
    const int mb = (id & 127) * 128;
    const int nbi = id >> 7;
    const int nb = nbi * 128;
    const int tid = threadIdx.x;

    if (role == 0){
        // ================= Q = x@W_Q + b_Q (fp32, exact-class) ===========
        typedef float (*pan_t)[16][132];
        pan_t sA = (pan_t)uLDS;                       // sA[p][k][m]
        pan_t sB = (pan_t)(uLDS + 16896);             // sB[p][k][n]
        const int tx = tid & 31, ty = tid >> 5;
        f32x2 acc2[8][2];
        #pragma unroll
        for (int i = 0; i < 8; ++i){
            acc2[i][0] = (f32x2){0.f, 0.f};
            acc2[i][1] = (f32x2){0.f, 0.f};
        }
        const int mA = tid >> 2, kA = (tid & 3) * 4;
        const int kB = tid >> 5, cB = (tid & 31) * 4;
        const float* xp = &x[(size_t)(mb + mA) * 512 + kA];
        const float* wp = &Wq[(size_t)kB * 512 + nb + cB];
        float4 pa = *(const float4*)xp;
        float4 pb = *(const float4*)wp;

        for (int k0 = 0; k0 < 512; k0 += 16){
            const int p = (k0 >> 4) & 1;
            sA[p][kA + 0][mA] = pa.x; sA[p][kA + 1][mA] = pa.y;
            sA[p][kA + 2][mA] = pa.z; sA[p][kA + 3][mA] = pa.w;
            *(float4*)&sB[p][kB][cB] = pb;
            __syncthreads();
            if (k0 < 496){
                pa = *(const float4*)(xp + k0 + 16);
                pb = *(const float4*)(wp + (size_t)(k0 + 16) * 512);
            }
            // software-pipelined kk loop: LDS reads one iteration ahead
            float4 va0 = *(const float4*)&sA[p][0][ty * 8];
            float4 va1 = *(const float4*)&sA[p][0][ty * 8 + 4];
            float4 vb  = *(const float4*)&sB[p][0][tx * 4];
            #pragma unroll
            for (int kk = 0; kk < 16; ++kk){
                float4 nva0, nva1, nvb;
                if (kk < 15){
                    nva0 = *(const float4*)&sA[p][kk + 1][ty * 8];
                    nva1 = *(const float4*)&sA[p][kk + 1][ty * 8 + 4];
                    nvb  = *(const float4*)&sB[p][kk + 1][tx * 4];
                }
                f32x2 a2[4], b2[2];
                a2[0] = (f32x2){va0.x, va0.y}; a2[1] = (f32x2){va0.z, va0.w};
                a2[2] = (f32x2){va1.x, va1.y}; a2[3] = (f32x2){va1.z, va1.w};
                b2[0] = (f32x2){vb.x, vb.y};   b2[1] = (f32x2){vb.z, vb.w};
                #pragma unroll
                for (int i = 0; i < 8; ++i){
                    if (i & 1){
                        PK_HI(acc2[i][0], a2[i >> 1], b2[0]);
                        PK_HI(acc2[i][1], a2[i >> 1], b2[1]);
                    } else {
                        PK_LO(acc2[i][0], a2[i >> 1], b2[0]);
                        PK_LO(acc2[i][1], a2[i >> 1], b2[1]);
                    }
                }
                if (kk < 15){ va0 = nva0; va1 = nva1; vb = nvb; }
            }
            // no trailing barrier: next iteration writes the other buffer
        }

        float4 vbq = *(const float4*)&bq[nb + tx * 4];
        const int h = nbi * 2 + (tx >> 4);
        const int d0 = (tx & 15) * 4;
        #pragma unroll
        for (int i = 0; i < 8; ++i){
            float o0 = acc2[i][0].x + vbq.x;
            float o1 = acc2[i][0].y + vbq.y;
            float o2 = acc2[i][1].x + vbq.z;
            float o3 = acc2[i][1].y + vbq.w;
            int m = mb + ty * 8 + i;
            int n = m >> 12, t = m & (T_ - 1);
            float4 q4; q4.x = o0; q4.y = o1; q4.z = o2; q4.w = o3;
            *(float4*)&Q[(size_t)m * 512 + nb + tx * 4] = q4;
            float ss = o0 * o0 + o1 * o1 + o2 * o2 + o3 * o3;
            #pragma unroll
            for (int s = 8; s >= 1; s >>= 1) ss += __shfl_xor(ss, s, 64);
            size_t rowb = (size_t)(h * N_ + n) * T_ + t;
            if ((tx & 15) == 0) qinv[rowb] = 1.f / (sqrtf(ss) + 1e-6f);
            ushort4 qb4;
            qb4.x = f2bf(o0); qb4.y = f2bf(o1); qb4.z = f2bf(o2); qb4.w = f2bf(o3);
            *(ushort4*)&Qbf[rowb * 64 + d0] = qb4;
        }
    } else {
        // ================= V = x@W_V + b_V (f16 MFMA) ====================
        if (tid >= 256) return;        // exited waves don't hold s_barrier
        u16* sA = (u16*)uLDS;                         // [128*40]
        u16* sB = (u16*)(uLDS + 10240);               // [128*40]
        const int w = tid >> 6, lane = tid & 63;
        const int quad = lane >> 4, cc = lane & 15;
        const int wm = (w & 1) * 64, wn = (w >> 1) * 64;
        f32x4 acc[4][4];
        #pragma unroll
        for (int i = 0; i < 4; ++i)
            #pragma unroll
            for (int j = 0; j < 4; ++j) acc[i][j] = (f32x4){0.f, 0.f, 0.f, 0.f};

        for (int k0 = 0; k0 < 512; k0 += 32){
            #pragma unroll
            for (int i = 0; i < 2; ++i){
                int idx = i * 256 + tid;               // 0..511
                int m = idx >> 2, ks = idx & 3;
                const float* xs = &x[(size_t)(mb + m) * 512 + k0 + ks * 8];
                float4 f0 = *(const float4*)xs;
                float4 f1 = *(const float4*)(xs + 4);
                short8 s;                               // == k_decXf's f2h
                s[0] = (short)f2h(f0.x); s[1] = (short)f2h(f0.y);
                s[2] = (short)f2h(f0.z); s[3] = (short)f2h(f0.w);
                s[4] = (short)f2h(f1.x); s[5] = (short)f2h(f1.y);
                s[6] = (short)f2h(f1.z); s[7] = (short)f2h(f1.w);
                *(short8*)&sA[m * 40 + ks * 8] = s;
                *(short8*)&sB[m * 40 + ks * 8] =
                    *(const short8*)&wvt[(size_t)(nb + m) * 512 + k0 + ks * 8];
            }
            __syncthreads();
            half8 a[4], b[4];
            #pragma unroll
            for (int i = 0; i < 4; ++i){
                a[i] = *(const half8*)&sA[(wm + i * 16 + cc) * 40 + quad * 8];
                b[i] = *(const half8*)&sB[(wn + i * 16 + cc) * 40 + quad * 8];
            }
            #pragma unroll
            for (int i = 0; i < 4; ++i)
                #pragma unroll
                for (int j = 0; j < 4; ++j)
                    acc[i][j] = __builtin_amdgcn_mfma_f32_16x16x32_f16(a[i], b[j], acc[i][j], 0, 0, 0);
            __syncthreads();
        }
        #pragma unroll
        for (int i = 0; i < 4; ++i)
            #pragma unroll
            for (int j = 0; j < 4; ++j){
                int c = nb + wn + j * 16 + cc;
                int hh = c >> 6, d = c & 63;
                float bi = bv[c];
                #pragma unroll
                for (int r = 0; r < 4; ++r){
                    int m = mb + wm + i * 16 + quad * 4 + r;
                    int n = m >> 12, t = m & (T_ - 1);
                    Vbf[((size_t)(hh * N_ + n) * T_ + t) * 64 + d] = f2bf(acc[i][j][r] + bi);
                }
            }
    }
}

// ---------------------------------------------------------------------------
// K2: rotations + argmax -> buckets[h][n][j*T + t]  (fp32, exact tie rules)
// ---------------------------------------------------------------------------
__global__ __launch_bounds__(256) void k_rot(const float* __restrict__ Q,
        const float* __restrict__ rot, int* __restrict__ buckets){
    const int tb = blockIdx.x * 32;
    const int n = blockIdx.y, h = blockIdx.z;
    const int hn = h * N_ + n;
    __shared__ float Rs[64 * 128];    // [f][i][jj]: f*128 + i*4 + jj
    __shared__ float Qs[32][64];
    const int tid = threadIdx.x;
    const float* rh = rot + (size_t)h * (64 * 128);   // [f][jj][i] contiguous
    for (int idx = tid; idx < 8192; idx += 256){
        int f = idx >> 7, rem = idx & 127, jj = rem >> 5, i2 = rem & 31;
        Rs[f * 128 + i2 * 4 + jj] = rh[idx];
    }
    for (int i = tid; i < 2048; i += 256){
        int t = i >> 6, f = i & 63;
        Qs[t][f] = Q[(size_t)(n * T_ + tb + t) * 512 + h * 64 + f];
    }
    __syncthreads();
    const int tx = tid & 31, tg = tid >> 5;   // tg: 8 groups of 4 t's
    f32x2 r2[4][2];                            // [tt][jj-pair]
    #pragma unroll
    for (int tt = 0; tt < 4; ++tt){
        r2[tt][0] = (f32x2){0.f, 0.f};
        r2[tt][1] = (f32x2){0.f, 0.f};
    }
    for (int f = 0; f < 64; f += 2){
        f32x2 qf[4];
        #pragma unroll
        for (int tt = 0; tt < 4; ++tt)
            qf[tt] = *(const f32x2*)&Qs[tg * 4 + tt][f];   // (q[f], q[f+1])
        float4 rv0 = *(const float4*)&Rs[f * 128 + tx * 4];
        float4 rv1 = *(const float4*)&Rs[(f + 1) * 128 + tx * 4];
        f32x2 b0[2], b1[2];
        b0[0] = (f32x2){rv0.x, rv0.y}; b0[1] = (f32x2){rv0.z, rv0.w};
        b1[0] = (f32x2){rv1.x, rv1.y}; b1[1] = (f32x2){rv1.z, rv1.w};
        #pragma unroll
        for (int tt = 0; tt < 4; ++tt){
            PK_LO(r2[tt][0], qf[tt], b0[0]);   // f   contribution
            PK_LO(r2[tt][1], qf[tt], b0[1]);
            PK_HI(r2[tt][0], qf[tt], b1[0]);   // f+1 contribution
            PK_HI(r2[tt][1], qf[tt], b1[1]);
        }
    }
    #pragma unroll
    for (int tt = 0; tt < 4; ++tt){
        #pragma unroll
        for (int jj = 0; jj < 4; ++jj){
            float rval = (jj < 2) ? r2[tt][0][jj] : r2[tt][1][jj - 2];
            // argmax over concat(r, -r); first-occurrence tie-break
            float bv = rval; int bi = tx;
            float nv = -bv;
            if (nv > bv){ bv = nv; bi = 32 + tx; }
            #pragma unroll
            for (int m = 16; m >= 1; m >>= 1){
                float ov = __shfl_xor(bv, m, 32);
                int   oi = __shfl_xor(bi, m, 32);
                if (ov > bv || (ov == bv && oi < bi)){ bv = ov; bi = oi; }
            }
            if (tx == 0){
                int t = tb + tg * 4 + tt;
                buckets[(size_t)hn * L_ + jj * T_ + t] = bi + jj * 64;
            }
        }
    }
}

// ---------------------------------------------------------------------------
// K3a: per-(hn,tile) 256-bin histogram. tile = 256 consecutive items.
// ---------------------------------------------------------------------------
__global__ __launch_bounds__(256) void k_hist(const int* __restrict__ buckets,
        int* __restrict__ hist){
    const int tile = blockIdx.x, hn = blockIdx.y;
    const int tid = threadIdx.x;
    __shared__ int h[256];
    h[tid] = 0;
    __syncthreads();
    int b = buckets[(size_t)hn * L_ + tile * 256 + tid];
    atomicAdd(&h[b], 1);
    __syncthreads();
    hist[((size_t)hn * 64 + tile) * 256 + tid] = h[tid];
}

// ---------------------------------------------------------------------------
// K3b: per-hn: in-place exclusive prefix of hist over tiles (per bucket),
//      then block scan of bucket totals -> bucketStart[hn][256]
// ---------------------------------------------------------------------------
__global__ __launch_bounds__(256) void k_scan(int* __restrict__ hist,
        int* __restrict__ bucketStart){
    const int hn = blockIdx.x;
    const int b = threadIdx.x;
    int* hh = hist + (size_t)hn * 64 * 256;
    int run = 0;
    for (int tl = 0; tl < 64; ++tl){
        int v = hh[tl * 256 + b];
        hh[tl * 256 + b] = run;      // exclusive within-bucket tile prefix
        run += v;
    }
    __shared__ int s[256];
    s[b] = run;
    __syncthreads();
    for (int off = 1; off < 256; off <<= 1){
        int add = (b >= off) ? s[b - off] : 0;
        __syncthreads();
        s[b] += add;
        __syncthreads();
    }
    bucketStart[hn * 256 + b] = s[b] - run;   // exclusive bucket start
}

// ---------------------------------------------------------------------------
// K3c: stable scatter: sticker[pos] = item index
// ---------------------------------------------------------------------------
__global__ __launch_bounds__(256) void k_scatter(const int* __restrict__ buckets,
        const int* __restrict__ offs, const int* __restrict__ bucketStart,
        int* __restrict__ sticker){
    const int tile = blockIdx.x, hn = blockIdx.y;
    const int tid = threadIdx.x;
    __shared__ int sb[256];
    const int i = tile * 256 + tid;
    const int b = buckets[(size_t)hn * L_ + i];
    sb[tid] = b;
    __syncthreads();
    int rank = 0;
    #pragma unroll 8
    for (int j = 0; j < 256; ++j){
        int v = sb[j];                         // broadcast read
        rank += (j < tid && v == b) ? 1 : 0;
    }
    int pos = bucketStart[hn * 256 + b]
            + offs[((size_t)hn * 64 + tile) * 256 + b]
            + rank;
    sticker[(size_t)hn * L_ + pos] = i;
}

// ---------------------------------------------------------------------------
// K4: chunked attention via MFMA. block = (chunk, n, h). 64 q x 128 k, DH=64
//     sP aliases sQ (dead after QK^T) -> ~34.5KB LDS -> 4 blocks/CU.
// ---------------------------------------------------------------------------
__global__ __launch_bounds__(256) void k_attn(const u16* __restrict__ Qbf,
        const u16* __restrict__ Vbf, const float* __restrict__ qinv,
        const int* __restrict__ buckets, const int* __restrict__ sticker,
        u16* __restrict__ o_hash, float* __restrict__ logit_hash){
    const int blk_c = blockIdx.x, n = blockIdx.y, h = blockIdx.z;
    const int hn = h * N_ + n;
    const int tid = threadIdx.x;
    const int w = tid >> 6, lane = tid & 63;
    const int quad = lane >> 4, cc = lane & 15;

    __shared__ __align__(16) u16 sQP[128 * 64];
    __shared__ __align__(16) u16 sVt[64 * 128];   // row = d, col = key row (V^T)
    __shared__ int s_idx[128], s_buck[128], s_t[128];
    __shared__ float s_inv[128];
    __shared__ float s_lse[64];
    u16* const sQ = sQP;
    u16* const sP = sQP;

    if (tid < 128){
        int cprev = (blk_c + CS_ - 1) & (CS_ - 1);
        int pos = (tid < 64) ? blk_c * 64 + tid : cprev * 64 + (tid - 64);
        int idx = sticker[(size_t)hn * L_ + pos];
        s_idx[tid] = idx;
        s_buck[tid] = buckets[(size_t)hn * L_ + idx];
        int t = idx & (T_ - 1);
        s_t[tid] = t;
        s_inv[tid] = qinv[(size_t)hn * T_ + t] * 0.125f;   // exact pow2 fold
    }
    __syncthreads();

    // ---- stage Q rows (b128) and V transposed (scalar b16) ----
    const int r0 = tid >> 3, l8 = tid & 7;
    #pragma unroll
    for (int it = 0; it < 4; ++it){
        int r = it * 32 + r0;
        size_t gb = ((size_t)hn * T_ + s_t[r]) * 64 + l8 * 8;
        short8 qv = *(const short8*)&Qbf[gb];
        *(short8*)&sQ[r * 64 + ((l8 ^ (r & 7)) * 8)] = qv;
        short8 vv = *(const short8*)&Vbf[gb];
        #pragma unroll
        for (int i = 0; i < 8; ++i){
            int d = l8 * 8 + i;
            sVt[d * 128 + (((r >> 3) ^ VSWZ(d)) * 8) + (r & 7)] = (u16)vv[i];
        }
    }
    __syncthreads();

    // ---- QK^T: wave w -> q-tile w; 2 k-chunks x 8 k-tiles ----
    f32x4 dacc[8];
    #pragma unroll
    for (int j = 0; j < 8; ++j) dacc[j] = (f32x4){0.f, 0.f, 0.f, 0.f};
    const int qrow = w * 16 + cc;
    #pragma unroll
    for (int kc = 0; kc < 2; ++kc){
        short8 afrag = *(const short8*)&sQ[qrow * 64 + (((kc * 4 + quad) ^ (cc & 7)) * 8)];
        #pragma unroll
        for (int kt = 0; kt < 8; ++kt){
            int krow = kt * 16 + cc;
            short8 bfrag = *(const short8*)&sQ[krow * 64 + (((kc * 4 + quad) ^ (cc & 7)) * 8)];
            dacc[kt] = __builtin_amdgcn_mfma_f32_16x16x32_bf16(afrag, bfrag, dacc[kt], 0, 0, 0);
        }
    }

    // ---- scale + masks + row softmax (rows: q = w*16 + quad*4 + reg) ----
    int bq[4], tq[4];
    #pragma unroll
    for (int r = 0; r < 4; ++r){
        int q = w * 16 + quad * 4 + r;
        bq[r] = s_buck[q]; tq[r] = s_t[q];
    }
    float mrow[4] = {-1e30f, -1e30f, -1e30f, -1e30f};
    #pragma unroll
    for (int kt = 0; kt < 8; ++kt){
        int kk = kt * 16 + cc;
        float inv = s_inv[kk];
        int bk = s_buck[kk], tk = s_t[kk];
        #pragma unroll
        for (int r = 0; r < 4; ++r){
            float d = dacc[kt][r] * inv;
            if (bk != bq[r]) d = -1e9f;
            if (tk == tq[r]) d = -1e-5f;
            dacc[kt][r] = d;
            mrow[r] = fmaxf(mrow[r], d);
        }
    }
    #pragma unroll
    for (int r = 0; r < 4; ++r)
        #pragma unroll
        for (int m = 8; m >= 1; m >>= 1)
            mrow[r] = fmaxf(mrow[r], __shfl_xor(mrow[r], m, 64));
    // exp once: keep p = exp(d - m) in dacc, sum it
    float srow[4] = {0.f, 0.f, 0.f, 0.f};
    #pragma unroll
    for (int kt = 0; kt < 8; ++kt)
        #pragma unroll
        for (int r = 0; r < 4; ++r){
            float e = __expf(dacc[kt][r] - mrow[r]);
            dacc[kt][r] = e;
            srow[r] += e;
        }
    #pragma unroll
    for (int r = 0; r < 4; ++r)
        #pragma unroll
        for (int m = 8; m >= 1; m >>= 1)
            srow[r] += __shfl_xor(srow[r], m, 64);
    float lse[4], pscale[4];
    #pragma unroll
    for (int r = 0; r < 4; ++r){
        lse[r] = mrow[r] + __logf(srow[r]);
        pscale[r] = 1.f / srow[r];
    }
    if (cc == 0){
        #pragma unroll
        for (int r = 0; r < 4; ++r) s_lse[w * 16 + quad * 4 + r] = lse[r];
    }

    // all waves' QK^T reads of sQ must complete before sP overwrites it;
    // barrier placed after softmax so that VALU overlaps slower waves' MFMA.
    __syncthreads();

    // ---- probs -> sP (C-layout scatter into swizzled A-layout tile) ----
    #pragma unroll
    for (int kt = 0; kt < 8; ++kt){
        int kk = kt * 16 + cc;
        #pragma unroll
        for (int r = 0; r < 4; ++r){
            int q = w * 16 + quad * 4 + r;
            sP[q * 128 + (((kk >> 3) ^ (q & 15)) * 8) + (kk & 7)] =
                f2bf(dacc[kt][r] * pscale[r]);
        }
    }
    __syncthreads();

    // ---- PV: wave w -> q-tile w; 4 k-chunks x 4 n-tiles ----
    f32x4 oacc[4];
    #pragma unroll
    for (int j = 0; j < 4; ++j) oacc[j] = (f32x4){0.f, 0.f, 0.f, 0.f};
    #pragma unroll
    for (int kc = 0; kc < 4; ++kc){
        short8 afrag = *(const short8*)&sP[qrow * 128 + (((kc * 4 + quad) ^ cc) * 8)];
        #pragma unroll
        for (int nt = 0; nt < 4; ++nt){
            int d = nt * 16 + cc;
            short8 bfrag = *(const short8*)&sVt[d * 128 + (((kc * 4 + quad) ^ VSWZ(d)) * 8)];
            oacc[nt] = __builtin_amdgcn_mfma_f32_16x16x32_bf16(afrag, bfrag, oacc[nt], 0, 0, 0);
        }
    }

    // ---- epilogue: scatter o (bf16) and logits to per-hash buffers ----
    #pragma unroll
    for (int r = 0; r < 4; ++r){
        int q = w * 16 + quad * 4 + r;
        int si = s_idx[q];
        int jj = si >> 12; int t = si & (T_ - 1);
        size_t base = ((size_t)(hn * NH_ + jj) * T_ + t) * 64;
        #pragma unroll
        for (int nt = 0; nt < 4; ++nt)
            o_hash[base + nt * 16 + cc] = f2bf(oacc[nt][r]);
    }
    if (tid < 64){
        int si = s_idx[tid]; int jj = si >> 12; int t = si & (T_ - 1);
        logit_hash[(size_t)(hn * NH_ + jj) * T_ + t] = s_lse[tid];
    }
}

// ---------------------------------------------------------------------------
// K5: combine over NH hash rounds per head + fused LayerNorm. block = (t,n)
// ---------------------------------------------------------------------------
__global__ __launch_bounds__(256) void k_comb(const u16* __restrict__ o_hash,
        const float* __restrict__ logit_hash, const float* __restrict__ gamma,
        const float* __restrict__ beta, float* __restrict__ out){
    const int t = blockIdx.x, n = blockIdx.y;
    const int tid = threadIdx.x;
    __shared__ float s_pw[32];
    __shared__ float s_x[512];
    __shared__ float s_red[8];
    __shared__ float s_mu, s_rs;
    if (tid < 32){
        int h = tid >> 2, j = tid & 3;
        s_pw[tid] = logit_hash[(size_t)((h * N_ + n) * NH_ + j) * T_ + t];
    }
    __syncthreads();
    if (tid < 8){
        int h = tid;
        float m = -1e30f;
        #pragma unroll
        for (int j = 0; j < 4; ++j) m = fmaxf(m, s_pw[h * 4 + j]);
        float l = 0.f;
        #pragma unroll
        for (int j = 0; j < 4; ++j) l += __expf(s_pw[h * 4 + j] - m);
        float ls = m + __logf(l);
        #pragma unroll
        for (int j = 0; j < 4; ++j) s_pw[h * 4 + j] = __expf(s_pw[h * 4 + j] - ls);
    }
    __syncthreads();
    float va[2];
    #pragma unroll
    for (int i = 0; i < 2; ++i){
        int cidx = tid + i * 256;
        int h = cidx >> 6, d = cidx & 63;
        size_t base = (size_t)((h * N_ + n) * NH_) * T_ * 64;
        float acc = 0.f;
        #pragma unroll
        for (int j = 0; j < 4; ++j)
            acc += s_pw[h * 4 + j] * bf2f(o_hash[base + ((size_t)j * T_ + t) * 64 + d]);
        s_x[cidx] = acc; va[i] = acc;
    }
    float s1 = va[0] + va[1];
    float s2 = va[0] * va[0] + va[1] * va[1];
    #pragma unroll
    for (int m = 32; m >= 1; m >>= 1){
        s1 += __shfl_xor(s1, m, 64);
        s2 += __shfl_xor(s2, m, 64);
    }
    const int lane = tid & 63, w = tid >> 6;
    if (lane == 0){ s_red[w] = s1; s_red[4 + w] = s2; }
    __syncthreads();
    if (tid == 0){
        float S1 = s_red[0] + s_red[1] + s_red[2] + s_red[3];
        float S2 = s_red[4] + s_red[5] + s_red[6] + s_red[7];
        float mu = S1 / 512.f;
        float var = S2 / 512.f - mu * mu;
        s_mu = mu; s_rs = 1.f / sqrtf(var + 1e-3f);
    }
    __syncthreads();
    #pragma unroll
    for (int i = 0; i < 2; ++i){
        int cidx = tid + i * 256;
        out[((size_t)(n * T_ + t)) * 512 + cidx] =
            gamma[cidx] * (s_x[cidx] - s_mu) * s_rs + beta[cidx];
    }
}

// ---------------------------------------------------------------------------
extern "C" void kernel_launch(void* const* d_in, const int* in_sizes, int n_in,
                              void* d_out, int out_size, void* d_ws, size_t ws_size,
                              hipStream_t stream){
    const float* x     = (const float*)d_in[0];
    const float* Wq    = (const float*)d_in[1];
    const float* bq    = (const float*)d_in[2];
    const float* Wv    = (const float*)d_in[3];
    const float* bv    = (const float*)d_in[4];
    const float* gamma = (const float*)d_in[5];
    const float* beta  = (const float*)d_in[6];
    const float* rot   = (const float*)d_in[7];
    char* ws = (char*)d_ws;
    // workspace layout. Time-disjoint overlap: Q fp32 [0,33.5MB) dead after
    // k_rot; o_hash [0,67.1MB) written only by k_attn (later in stream).
    float* Q        = (float*)(ws + 0);               // 33,554,432 B (k_qv..k_rot)
    u16*   o_hash   = (u16*)  (ws + 0);               // 67,108,864 B (k_attn..k_comb)
    u16*   Qbf      = (u16*)  (ws + 67108864);        // 16,777,216 B
    u16*   Vbf      = (u16*)  (ws + 83886080);        // 16,777,216 B
    float* qinv     = (float*)(ws + 100663296);       //    524,288 B
    int*   buckets  = (int*)  (ws + 101187584);       //  2,097,152 B
    int*   sticker  = (int*)  (ws + 103284736);       //  2,097,152 B
    float* logit    = (float*)(ws + 105381888);       //  2,097,152 B
    int*   hist     = (int*)  (ws + 107479040);       //  2,097,152 B
    int*   bstart   = (int*)  (ws + 109576192);       //     32,768 B
    u16*   wvt      = (u16*)  (ws + 109608960);       //    524,288 B

    hipLaunchKernelGGL(k_decWv,   dim3(16, 16),     dim3(256), 0, stream,
                       Wv, wvt);
    hipLaunchKernelGGL(k_qv,      dim3(1024),       dim3(512), 0, stream,
                       x, Wq, bq, wvt, bv, Q, Qbf, qinv, Vbf);
    hipLaunchKernelGGL(k_rot,     dim3(128, 4, 8),  dim3(256), 0, stream,
                       Q, rot, buckets);
    hipLaunchKernelGGL(k_hist,    dim3(64, 32),     dim3(256), 0, stream,
                       buckets, hist);
    hipLaunchKernelGGL(k_scan,    dim3(32),         dim3(256), 0, stream,
                       hist, bstart);
    hipLaunchKernelGGL(k_scatter, dim3(64, 32),     dim3(256), 0, stream,
                       buckets, hist, bstart, sticker);
    hipLaunchKernelGGL(k_attn,    dim3(256, 4, 8),  dim3(256), 0, stream,
                       Qbf, Vbf, qinv, buckets, sticker, o_hash, logit);
    hipLaunchKernelGGL(k_comb,    dim3(4096, 4),    dim3(256), 0, stream,
                       o_hash, logit, gamma, beta, (float*)d_out);
}